// Round 13
// baseline (2257.441 us; speedup 1.0000x reference)
//
#include <hip/hip_runtime.h>
#include <hip/hip_bf16.h>

// MnistModelDP: 2-layer LSTM (H=512) over T=64 frames of 128, B=2048, then proj to 10.
// v12: persistent kernel with XCD-LOCAL DEPENDENCY GROUPS.
//  - group = rowtile (16 groups x 16 blocks = 2 layers x 8 hcb), owns batch rows
//    [g*128,+128) of BOTH layers -> all h producer/consumer edges intra-group.
//  - startup check (s_getreg HW_REG_XCC_ID, m09): if every group is on one XCD ->
//    h stores plain (land in that XCD's L2), h loads sc0/aux=1 (bypass stale L1, hit L2).
//    Else fall back grid-wide to sc1 both sides (v10-proven). Mapping-independent.
//  - c state in registers (v9-verified); NO gates exchange: B tile interleaves gates
//    (j = hc16*64 + gate*16 + lc) so each wave holds all 4 gates for its 16 hcols.
//  - counted-vmcnt K-loop (v10/v11-verified): B dbuf, A tri-buf, vmcnt(8/6/0), raw
//    s_barrier, no mid-loop drain. Per-group barriers; no grid sync after startup.
// Tile BM=128 x BN=256, 8 waves (2x4 of 64x64), BK=64, granule-XOR swizzle via
// pre-swizzled source + linear global_load_lds dest (proven v4-v11). fp16 MFMA.

typedef _Float16 f16x8 __attribute__((ext_vector_type(8)));
typedef float f32x4 __attribute__((ext_vector_type(4)));

#define Bsz 2048
#define Lsz 8192
#define Tsz 64
#define HS ((size_t)Bsz * 512)

__global__ void cvt_f32_f16(const float* __restrict__ src, _Float16* __restrict__ dst, int n4) {
    int stride = gridDim.x * blockDim.x;
    for (int i = blockIdx.x * blockDim.x + threadIdx.x; i < n4; i += stride) {
        float4 v = ((const float4*)src)[i];
        union { _Float16 h[4]; ushort4 u; } o;
        o.h[0] = (_Float16)v.x; o.h[1] = (_Float16)v.y;
        o.h[2] = (_Float16)v.z; o.h[3] = (_Float16)v.w;
        ((ushort4*)dst)[i] = o.u;
    }
}

// pack [2048, K1] W_ih (f32) and [2048, 512] W_hh (f32) -> [2048, K1+512] f16
__global__ void pack_w(const float* __restrict__ Wih, const float* __restrict__ Whh,
                       _Float16* __restrict__ dst, int K1) {
    int KT = K1 + 512;
    int n4 = 2048 * KT / 4;
    int stride = gridDim.x * blockDim.x;
    for (int i = blockIdx.x * blockDim.x + threadIdx.x; i < n4; i += stride) {
        int row = i / (KT / 4);
        int col = (i % (KT / 4)) * 4;
        const float* s = (col < K1) ? (Wih + (size_t)row * K1 + col)
                                    : (Whh + (size_t)row * 512 + (col - K1));
        float4 v = *(const float4*)s;
        union { _Float16 h[4]; ushort4 u; } o;
        o.h[0] = (_Float16)v.x; o.h[1] = (_Float16)v.y;
        o.h[2] = (_Float16)v.z; o.h[3] = (_Float16)v.w;
        ((ushort4*)dst)[i] = o.u;
    }
}

__device__ __forceinline__ float fsig(float x)  { return 1.0f / (1.0f + __expf(-x)); }
__device__ __forceinline__ float ftanh(float x) { return 1.0f - 2.0f / (__expf(2.0f * x) + 1.0f); }

// AUX=0 plain cached; AUX=1 sc0 (bypass L1, read own-XCD L2); AUX=16 sc1 (IF coherent).
template<int AUX>
__device__ __forceinline__ void gll16(const _Float16* src, char* dst) {
    __builtin_amdgcn_global_load_lds(
        (const __attribute__((address_space(1))) void*)src,
        (__attribute__((address_space(3))) void*)dst, 16, 0, AUX);
}

// B tile (256 gate-cols x 64, 32KB), INTERLEAVED layout: LDS row j -> W row
// gate*512 + hcb*64 + hc16*16 + lc  with  hc16=j>>6, gate=(j>>4)&3, lc=j&15.
// Granule-XOR swizzle via pre-swizzled source col (both-sides rule, proven v4-v11).
template<int K1>
__device__ __forceinline__ void stageB(
    const _Float16* __restrict__ Wcat, int hcb, int k0, char* buf, int tid)
{
    constexpr int KT = K1 + 512;
    const int wv = tid >> 6;
#pragma unroll
    for (int qq = 0; qq < 4; ++qq) {
        const int j  = qq * 64 + (tid >> 3);
        const int cg = (((tid & 7) ^ (j & 7)) << 3);
        const int wrow = ((j >> 4) & 3) * 512 + hcb * 64 + (j >> 6) * 16 + (j & 15);
        gll16<0>(Wcat + (size_t)wrow * KT + k0 + cg, buf + qq * 8192 + wv * 1024);
    }
}

// A tile (128 rows x 64, 16KB). k0 mult of 64, K1%64==0 -> uniform branch.
template<int K1, int AUX1, int AUX2>
__device__ __forceinline__ void stageA(
    const _Float16* __restrict__ A1, int lda1,
    const _Float16* __restrict__ A2,
    int rowtile, int k0, char* buf, int tid)
{
    const int wv = tid >> 6;
#pragma unroll
    for (int qq = 0; qq < 2; ++qq) {
        const int row  = qq * 64 + (tid >> 3);
        const int cg   = (((tid & 7) ^ (row & 7)) << 3);
        const int brow = rowtile * 128 + row;
        char* d = buf + qq * 8192 + wv * 1024;
        if (k0 < K1) gll16<AUX1>(A1 + (size_t)brow * lda1 + k0 + cg, d);
        else         gll16<AUX2>(A2 + (size_t)brow * 512 + (k0 - K1) + cg, d);
    }
}

// One LSTM step tile: 128 rows x 256 gate-cols, K=K1+512, BK=64. Counted-vmcnt
// pipeline (verified v10/v11). Wave wc holds gates 0..3 (cf) for hcols
// hcb*64+wc*16+llo -> cell update fully in registers, c persistent in creg[16].
// MFMA 16x16x32 f16 layouts (passed v2/v4-v11).
template<int K1, int AUX1, int AUX2, int SSC1>
__device__ __forceinline__ void step_p(
    const _Float16* __restrict__ A1, int lda1,
    const _Float16* __restrict__ A2,
    const _Float16* __restrict__ Wcat,
    const float* __restrict__ bias,
    float* creg,                          // [16] registers
    _Float16* __restrict__ h_out,
    int rowtile, int hcb, char* lds)
{
    constexpr int KT  = K1 + 512;
    constexpr int NIT = KT / 64;
    const int tid = threadIdx.x;
    const int ln  = tid & 63;
    const int wv  = tid >> 6;
    const int llo = ln & 15, lhi = ln >> 4;
    const int wr  = wv >> 2, wc = wv & 3;

    f32x4 acc[4][4] = {};   // [row-frag mi][gate cf]

    stageA<K1, AUX1, AUX2>(A1, lda1, A2, rowtile, 0, lds + 65536, tid);
    stageB<K1>(Wcat, hcb, 0, lds, tid);
    stageA<K1, AUX1, AUX2>(A1, lda1, A2, rowtile, 64, lds + 65536 + 16384, tid);

    for (int it = 0; it < NIT; ++it) {
        if (it + 1 < NIT)
            stageB<K1>(Wcat, hcb, (it + 1) * 64, lds + ((it + 1) & 1) * 32768, tid);
        if (it + 2 < NIT)
            stageA<K1, AUX1, AUX2>(A1, lda1, A2, rowtile, (it + 2) * 64,
                                   lds + 65536 + ((it + 2) % 3) * 16384, tid);
        if (it < NIT - 2)       asm volatile("s_waitcnt vmcnt(8)" ::: "memory");
        else if (it == NIT - 2) asm volatile("s_waitcnt vmcnt(6)" ::: "memory");
        else                    asm volatile("s_waitcnt vmcnt(0)" ::: "memory");
        __builtin_amdgcn_s_barrier();
        __builtin_amdgcn_sched_barrier(0);

        char* bb = lds + (it & 1) * 32768;
        char* ab = lds + 65536 + (it % 3) * 16384;
#pragma unroll
        for (int ks = 0; ks < 2; ++ks) {
            const int gsw = (((ks * 4 + lhi) ^ (llo & 7)) << 4);
            f16x8 a[4], b[4];
#pragma unroll
            for (int mi = 0; mi < 4; ++mi)
                a[mi] = *(const f16x8*)(ab + (wr * 64 + mi * 16 + llo) * 128 + gsw);
#pragma unroll
            for (int cf = 0; cf < 4; ++cf)
                b[cf] = *(const f16x8*)(bb + (wc * 64 + cf * 16 + llo) * 128 + gsw);
#pragma unroll
            for (int mi = 0; mi < 4; ++mi)
#pragma unroll
                for (int cf = 0; cf < 4; ++cf)
                    acc[mi][cf] = __builtin_amdgcn_mfma_f32_16x16x32_f16(
                        a[mi], b[cf], acc[mi][cf], 0, 0, 0);
        }
        __builtin_amdgcn_s_barrier();
        __builtin_amdgcn_sched_barrier(0);
    }

    // in-register cell update: thread owns 16 (row) cells x 1 hcol, all 4 gates in acc.
    const int hcol = hcb * 64 + wc * 16 + llo;
    float bz[4];
#pragma unroll
    for (int g = 0; g < 4; ++g) bz[g] = bias[g * 512 + hcol];
#pragma unroll
    for (int mi = 0; mi < 4; ++mi)
#pragma unroll
        for (int rr = 0; rr < 4; ++rr) {
            const int row = rowtile * 128 + wr * 64 + mi * 16 + lhi * 4 + rr;
            float iv = acc[mi][0][rr] + bz[0];
            float fv = acc[mi][1][rr] + bz[1];
            float gv = acc[mi][2][rr] + bz[2];
            float ov = acc[mi][3][rr] + bz[3];
            float cn = fsig(fv) * creg[mi * 4 + rr] + fsig(iv) * ftanh(gv);
            creg[mi * 4 + rr] = cn;
            float hn = fsig(ov) * ftanh(cn);
            union { _Float16 hf; unsigned short hu; } u; u.hf = (_Float16)hn;
            unsigned short* hp = (unsigned short*)(h_out + (size_t)row * 512 + hcol);
            if (SSC1) __hip_atomic_store(hp, u.hu, __ATOMIC_RELAXED, __HIP_MEMORY_SCOPE_AGENT);
            else      *hp = u.hu;
        }
}

// Round loop, templated on coherence mode (uniform across grid after startup check).
template<int AUXH, int SSC1>
__device__ __forceinline__ void run_rounds(
    int layer, int rowtile, int hcb, int group,
    const _Float16* xb16, const _Float16* Wc0, const float* b0,
    const _Float16* Wc1, const float* b1,
    _Float16* h0a, _Float16* h0b, _Float16* h1a, _Float16* h1b,
    const _Float16* hz, unsigned* cnt, char* lds, float* creg)
{
    _Float16* h0r[2] = {h0a, h0b};
    _Float16* h1r[2] = {h1a, h1b};
    for (int r = 0; r <= Tsz; ++r) {
        if (layer == 0) {
            if (r < Tsz) {
                const int t = r;
                const _Float16* hp = t ? h0r[(t - 1) & 1] : hz;
                step_p<128, 0, AUXH, SSC1>(xb16 + (size_t)t * 128, Lsz, hp, Wc0, b0,
                                           creg, h0r[t & 1], rowtile, hcb, lds);
            }
        } else {
            if (r >= 1) {
                const int t = r - 1;
                const _Float16* hp = t ? h1r[(t - 1) & 1] : hz;
                step_p<512, AUXH, AUXH, SSC1>(h0r[t & 1], 512, hp, Wc1, b1,
                                              creg, h1r[t & 1], rowtile, hcb, lds);
            }
        }
        if (r < Tsz) {
            // per-group barrier: 16 arrivals; __syncthreads drains vmcnt first.
            __syncthreads();
            if (threadIdx.x == 0) {
                unsigned* cp = cnt + group * 16;
                __hip_atomic_fetch_add(cp, 1u, __ATOMIC_RELAXED, __HIP_MEMORY_SCOPE_AGENT);
                const unsigned target = 16u * (r + 1);
                while (__hip_atomic_load(cp, __ATOMIC_RELAXED, __HIP_MEMORY_SCOPE_AGENT) < target)
                    __builtin_amdgcn_s_sleep(1);
            }
            __syncthreads();
            __builtin_amdgcn_sched_barrier(0);
        }
    }
}

// 256 blocks, 1/CU. Decode: x=bid&7, m=bid>>3, sub=m&15: layer=sub>>3, hcb=sub&7;
// group = rowtile = x*2 + (m>>4). Group's 16 bids all = x (mod 8) -> one XCD under
// default round-robin; verified at runtime via HW_REG_XCC_ID, else sc1 fallback.
__global__ __launch_bounds__(512, 1) void lstm_persist(
    const _Float16* __restrict__ xb16,
    const _Float16* __restrict__ Wc0, const float* __restrict__ b0,
    const _Float16* __restrict__ Wc1, const float* __restrict__ b1,
    _Float16* __restrict__ h0a, _Float16* __restrict__ h0b,
    _Float16* __restrict__ h1a, _Float16* __restrict__ h1b,
    const _Float16* __restrict__ hz,
    unsigned* __restrict__ cnt,    // 16 groups x 16 uints
    unsigned* __restrict__ gcnt,   // global startup counter
    unsigned* __restrict__ xcds,   // 256 block xcc ids
    unsigned* __restrict__ flag)   // 0 = all groups XCD-local
{
    __shared__ __align__(16) char lds[114688];
    const int bid     = blockIdx.x;
    const int x       = bid & 7;
    const int m       = bid >> 3;
    const int sub     = m & 15;
    const int layer   = sub >> 3;
    const int hcb     = sub & 7;
    const int grp_loc = m >> 4;
    const int group   = x * 2 + grp_loc;
    const int rowtile = group;

    unsigned myxcc;
    asm volatile("s_getreg_b32 %0, hwreg(HW_REG_XCC_ID)" : "=s"(myxcc));

    if (threadIdx.x == 0)
        __hip_atomic_store(&xcds[bid], myxcc, __ATOMIC_RELAXED, __HIP_MEMORY_SCOPE_AGENT);
    __syncthreads();
    if (threadIdx.x == 0) {
        __hip_atomic_fetch_add(gcnt, 1u, __ATOMIC_RELAXED, __HIP_MEMORY_SCOPE_AGENT);
        while (__hip_atomic_load(gcnt, __ATOMIC_RELAXED, __HIP_MEMORY_SCOPE_AGENT) < 256u)
            __builtin_amdgcn_s_sleep(1);
        unsigned bad = 0;
        for (int j = 0; j < 16; ++j) {
            const int mb = x + 8 * (grp_loc * 16 + j);
            unsigned v = __hip_atomic_load(&xcds[mb], __ATOMIC_RELAXED, __HIP_MEMORY_SCOPE_AGENT);
            bad |= (v != myxcc) ? 1u : 0u;
        }
        if (bad)
            __hip_atomic_fetch_add(flag, 1u, __ATOMIC_RELAXED, __HIP_MEMORY_SCOPE_AGENT);
        __hip_atomic_fetch_add(gcnt, 1u, __ATOMIC_RELAXED, __HIP_MEMORY_SCOPE_AGENT);
        while (__hip_atomic_load(gcnt, __ATOMIC_RELAXED, __HIP_MEMORY_SCOPE_AGENT) < 512u)
            __builtin_amdgcn_s_sleep(1);
    }
    __syncthreads();
    const unsigned f = __hip_atomic_load(flag, __ATOMIC_RELAXED, __HIP_MEMORY_SCOPE_AGENT);

    float creg[16];
#pragma unroll
    for (int i = 0; i < 16; ++i) creg[i] = 0.0f;

    if (f == 0)
        run_rounds<1, 0>(layer, rowtile, hcb, group, xb16, Wc0, b0, Wc1, b1,
                         h0a, h0b, h1a, h1b, hz, cnt, lds, creg);
    else
        run_rounds<16, 1>(layer, rowtile, hcb, group, xb16, Wc0, b0, Wc1, b1,
                          h0a, h0b, h1a, h1b, hz, cnt, lds, creg);
}

__global__ void proj_kernel(const _Float16* __restrict__ h1,
                            const float* __restrict__ Wout,  // [10, 512]
                            const float* __restrict__ bout,  // [10]
                            float* __restrict__ out)         // [2048, 10]
{
    int tid = blockIdx.x * blockDim.x + threadIdx.x;
    if (tid >= Bsz * 10) return;
    int b = tid / 10, o = tid % 10;
    float s = bout[o];
    const _Float16* hrow = h1 + (size_t)b * 512;
    const float* wrow = Wout + (size_t)o * 512;
    for (int k = 0; k < 512; ++k) s += (float)hrow[k] * wrow[k];
    out[tid] = s;
}

extern "C" void kernel_launch(void* const* d_in, const int* in_sizes, int n_in,
                              void* d_out, int out_size, void* d_ws, size_t ws_size,
                              hipStream_t stream) {
    const float* xb    = (const float*)d_in[0];
    const float* W_ih0 = (const float*)d_in[1];
    const float* W_hh0 = (const float*)d_in[2];
    const float* b0    = (const float*)d_in[3];
    const float* W_ih1 = (const float*)d_in[4];
    const float* W_hh1 = (const float*)d_in[5];
    const float* b1    = (const float*)d_in[6];
    const float* W_out = (const float*)d_in[7];
    const float* b_out = (const float*)d_in[8];
    float* out = (float*)d_out;

    char* ws = (char*)d_ws;
    size_t off = 0;
    auto alloc = [&](size_t bytes) -> void* {
        void* p = ws + off;
        off += (bytes + 255) & ~(size_t)255;
        return p;
    };
    // ~49 MB << 256 MiB ws
    _Float16* xb16 = (_Float16*)alloc((size_t)Bsz * Lsz * 2);
    _Float16* Wc0  = (_Float16*)alloc((size_t)2048 * 640 * 2);
    _Float16* Wc1  = (_Float16*)alloc((size_t)2048 * 1024 * 2);
    _Float16* h0a  = (_Float16*)alloc(HS * 2);
    _Float16* h0b  = (_Float16*)alloc(HS * 2);
    _Float16* h1a  = (_Float16*)alloc(HS * 2);
    _Float16* h1b  = (_Float16*)alloc(HS * 2);
    _Float16* hz   = (_Float16*)alloc(HS * 2);
    unsigned* cnt  = (unsigned*)alloc(16 * 16 * 4);
    unsigned* gcnt = (unsigned*)alloc(256);
    unsigned* xcds = (unsigned*)alloc(256 * 4);
    unsigned* flag = (unsigned*)alloc(256);

    cvt_f32_f16<<<2048, 256, 0, stream>>>(xb, xb16, Bsz * Lsz / 4);
    pack_w<<<1280, 256, 0, stream>>>(W_ih0, W_hh0, Wc0, 128);
    pack_w<<<2048, 256, 0, stream>>>(W_ih1, W_hh1, Wc1, 512);

    hipMemsetAsync(hz, 0, HS * 2, stream);
    hipMemsetAsync(cnt, 0, 16 * 16 * 4, stream);
    hipMemsetAsync(gcnt, 0, 256, stream);
    hipMemsetAsync(xcds, 0, 256 * 4, stream);
    hipMemsetAsync(flag, 0, 256, stream);

    lstm_persist<<<dim3(256), 512, 0, stream>>>(
        xb16, Wc0, b0, Wc1, b1, h0a, h0b, h1a, h1b, hz, cnt, gcnt, xcds, flag);

    // final h1 = step t=63 -> h1r[63&1] = h1b
    proj_kernel<<<(Bsz * 10 + 255) / 256, 256, 0, stream>>>(h1b, W_out, b_out, out);
}

// Round 15
// 2149.837 us; speedup vs baseline: 1.0501x; 1.0501x over previous
//
#include <hip/hip_runtime.h>
#include <hip/hip_bf16.h>

// MnistModelDP: 2-layer LSTM (H=512) over T=64 frames of 128, B=2048, then proj to 10.
// v13: persistent kernel; weight-partition chosen over h-partition:
//  - hcb = bid&7 -> under default bid%8->XCD round-robin each XCD hosts ONE 851KB weight
//    strip pair (both layers, all rowtiles) -> weights L2-resident all 64 rounds.
//    (v12's group-per-rowtile decode put 6.7MB of weights on every XCD -> L2 thrash ->
//    50MB/round L3 re-stream = its 36us/round. v10 had the same hidden defect.)
//  - h cross-XCD by construction -> sc1 both sides (v7/v10-proven, mapping-independent):
//    producer sc1 stores to IF, consumer sc1 global_load_lds; latency covered by the
//    2-deep A-ring of the counted-vmcnt pipeline (vmcnt 8/6/0, refchecked v10/v11/v12).
//  - c in registers; interleaved-B gate layout -> in-register cell update, no LDS
//    exchange, 0 bank conflicts (v12-verified).
//  - per-rowtile group barrier (16 arrivals: 2 layers x 8 hcb).
// Tile BM=128 x BN=256, 8 waves (2x4 of 64x64), BK=64, granule-XOR swizzle via
// pre-swizzled source + linear global_load_lds dest (proven v4-v12). fp16 MFMA.

typedef _Float16 f16x8 __attribute__((ext_vector_type(8)));
typedef float f32x4 __attribute__((ext_vector_type(4)));

#define Bsz 2048
#define Lsz 8192
#define Tsz 64
#define HS ((size_t)Bsz * 512)

__global__ void cvt_f32_f16(const float* __restrict__ src, _Float16* __restrict__ dst, int n4) {
    int stride = gridDim.x * blockDim.x;
    for (int i = blockIdx.x * blockDim.x + threadIdx.x; i < n4; i += stride) {
        float4 v = ((const float4*)src)[i];
        union { _Float16 h[4]; ushort4 u; } o;
        o.h[0] = (_Float16)v.x; o.h[1] = (_Float16)v.y;
        o.h[2] = (_Float16)v.z; o.h[3] = (_Float16)v.w;
        ((ushort4*)dst)[i] = o.u;
    }
}

// pack [2048, K1] W_ih (f32) and [2048, 512] W_hh (f32) -> [2048, K1+512] f16
__global__ void pack_w(const float* __restrict__ Wih, const float* __restrict__ Whh,
                       _Float16* __restrict__ dst, int K1) {
    int KT = K1 + 512;
    int n4 = 2048 * KT / 4;
    int stride = gridDim.x * blockDim.x;
    for (int i = blockIdx.x * blockDim.x + threadIdx.x; i < n4; i += stride) {
        int row = i / (KT / 4);
        int col = (i % (KT / 4)) * 4;
        const float* s = (col < K1) ? (Wih + (size_t)row * K1 + col)
                                    : (Whh + (size_t)row * 512 + (col - K1));
        float4 v = *(const float4*)s;
        union { _Float16 h[4]; ushort4 u; } o;
        o.h[0] = (_Float16)v.x; o.h[1] = (_Float16)v.y;
        o.h[2] = (_Float16)v.z; o.h[3] = (_Float16)v.w;
        ((ushort4*)dst)[i] = o.u;
    }
}

__device__ __forceinline__ float fsig(float x)  { return 1.0f / (1.0f + __expf(-x)); }
__device__ __forceinline__ float ftanh(float x) { return 1.0f - 2.0f / (__expf(2.0f * x) + 1.0f); }

// AUX=0 plain cached (weights/x, L2-resident); AUX=16 sc1 (IF-coherent, h).
template<int AUX>
__device__ __forceinline__ void gll16(const _Float16* src, char* dst) {
    __builtin_amdgcn_global_load_lds(
        (const __attribute__((address_space(1))) void*)src,
        (__attribute__((address_space(3))) void*)dst, 16, 0, AUX);
}

// B tile (256 gate-cols x 64, 32KB), INTERLEAVED layout: LDS row j -> W row
// gate*512 + hcb*64 + hc16*16 + lc  with  hc16=j>>6, gate=(j>>4)&3, lc=j&15.
// Granule-XOR swizzle via pre-swizzled source col (both-sides rule, proven v4-v12).
template<int K1>
__device__ __forceinline__ void stageB(
    const _Float16* __restrict__ Wcat, int hcb, int k0, char* buf, int tid)
{
    constexpr int KT = K1 + 512;
    const int wv = tid >> 6;
#pragma unroll
    for (int qq = 0; qq < 4; ++qq) {
        const int j  = qq * 64 + (tid >> 3);
        const int cg = (((tid & 7) ^ (j & 7)) << 3);
        const int wrow = ((j >> 4) & 3) * 512 + hcb * 64 + (j >> 6) * 16 + (j & 15);
        gll16<0>(Wcat + (size_t)wrow * KT + k0 + cg, buf + qq * 8192 + wv * 1024);
    }
}

// A tile (128 rows x 64, 16KB). k0 mult of 64, K1%64==0 -> uniform branch.
template<int K1, int AUX1, int AUX2>
__device__ __forceinline__ void stageA(
    const _Float16* __restrict__ A1, int lda1,
    const _Float16* __restrict__ A2,
    int rowtile, int k0, char* buf, int tid)
{
    const int wv = tid >> 6;
#pragma unroll
    for (int qq = 0; qq < 2; ++qq) {
        const int row  = qq * 64 + (tid >> 3);
        const int cg   = (((tid & 7) ^ (row & 7)) << 3);
        const int brow = rowtile * 128 + row;
        char* d = buf + qq * 8192 + wv * 1024;
        if (k0 < K1) gll16<AUX1>(A1 + (size_t)brow * lda1 + k0 + cg, d);
        else         gll16<AUX2>(A2 + (size_t)brow * 512 + (k0 - K1) + cg, d);
    }
}

// One LSTM step tile: 128 rows x 256 gate-cols, K=K1+512, BK=64. Counted-vmcnt
// pipeline (verified v10-v12). Wave wc holds gates 0..3 (cf) for hcols hcb*64+wc*16+llo
// -> cell update fully in registers, c persistent in creg[16], h stored sc1.
// MFMA 16x16x32 f16 layouts (passed v2/v4-v12).
template<int K1, int AUX1, int AUX2>
__device__ __forceinline__ void step_p(
    const _Float16* __restrict__ A1, int lda1,
    const _Float16* __restrict__ A2,
    const _Float16* __restrict__ Wcat,
    const float* __restrict__ bias,
    float* creg,                          // [16] registers
    _Float16* __restrict__ h_out,         // sc1 stores -> IF
    int rowtile, int hcb, char* lds)
{
    constexpr int KT  = K1 + 512;
    constexpr int NIT = KT / 64;
    const int tid = threadIdx.x;
    const int ln  = tid & 63;
    const int wv  = tid >> 6;
    const int llo = ln & 15, lhi = ln >> 4;
    const int wr  = wv >> 2, wc = wv & 3;

    f32x4 acc[4][4] = {};   // [row-frag mi][gate cf]

    stageA<K1, AUX1, AUX2>(A1, lda1, A2, rowtile, 0, lds + 65536, tid);
    stageB<K1>(Wcat, hcb, 0, lds, tid);
    stageA<K1, AUX1, AUX2>(A1, lda1, A2, rowtile, 64, lds + 65536 + 16384, tid);

    for (int it = 0; it < NIT; ++it) {
        if (it + 1 < NIT)
            stageB<K1>(Wcat, hcb, (it + 1) * 64, lds + ((it + 1) & 1) * 32768, tid);
        if (it + 2 < NIT)
            stageA<K1, AUX1, AUX2>(A1, lda1, A2, rowtile, (it + 2) * 64,
                                   lds + 65536 + ((it + 2) % 3) * 16384, tid);
        if (it < NIT - 2)       asm volatile("s_waitcnt vmcnt(8)" ::: "memory");
        else if (it == NIT - 2) asm volatile("s_waitcnt vmcnt(6)" ::: "memory");
        else                    asm volatile("s_waitcnt vmcnt(0)" ::: "memory");
        __builtin_amdgcn_s_barrier();
        __builtin_amdgcn_sched_barrier(0);

        char* bb = lds + (it & 1) * 32768;
        char* ab = lds + 65536 + (it % 3) * 16384;
#pragma unroll
        for (int ks = 0; ks < 2; ++ks) {
            const int gsw = (((ks * 4 + lhi) ^ (llo & 7)) << 4);
            f16x8 a[4], b[4];
#pragma unroll
            for (int mi = 0; mi < 4; ++mi)
                a[mi] = *(const f16x8*)(ab + (wr * 64 + mi * 16 + llo) * 128 + gsw);
#pragma unroll
            for (int cf = 0; cf < 4; ++cf)
                b[cf] = *(const f16x8*)(bb + (wc * 64 + cf * 16 + llo) * 128 + gsw);
#pragma unroll
            for (int mi = 0; mi < 4; ++mi)
#pragma unroll
                for (int cf = 0; cf < 4; ++cf)
                    acc[mi][cf] = __builtin_amdgcn_mfma_f32_16x16x32_f16(
                        a[mi], b[cf], acc[mi][cf], 0, 0, 0);
        }
        __builtin_amdgcn_s_barrier();
        __builtin_amdgcn_sched_barrier(0);
    }

    // in-register cell update: thread owns 16 row-cells x 1 hcol, all 4 gates in acc.
    const int hcol = hcb * 64 + wc * 16 + llo;
    float bz[4];
#pragma unroll
    for (int g = 0; g < 4; ++g) bz[g] = bias[g * 512 + hcol];
#pragma unroll
    for (int mi = 0; mi < 4; ++mi)
#pragma unroll
        for (int rr = 0; rr < 4; ++rr) {
            const int row = rowtile * 128 + wr * 64 + mi * 16 + lhi * 4 + rr;
            float iv = acc[mi][0][rr] + bz[0];
            float fv = acc[mi][1][rr] + bz[1];
            float gv = acc[mi][2][rr] + bz[2];
            float ov = acc[mi][3][rr] + bz[3];
            float cn = fsig(fv) * creg[mi * 4 + rr] + fsig(iv) * ftanh(gv);
            creg[mi * 4 + rr] = cn;
            float hn = fsig(ov) * ftanh(cn);
            union { _Float16 hf; unsigned short hu; } u; u.hf = (_Float16)hn;
            __hip_atomic_store((unsigned short*)(h_out + (size_t)row * 512 + hcol), u.hu,
                               __ATOMIC_RELAXED, __HIP_MEMORY_SCOPE_AGENT);
        }
}

// 256 blocks, 1/CU. Decode: hcb=bid&7 (weight strip pinned per XCD under default
// round-robin -- perf heuristic only); q=bid>>3: layer=q&1, rowtile=q>>1.
// Group = rowtile: 16 blocks (2 layers x 8 hcb); all h deps intra-group; correctness
// mapping-independent (h via sc1/IF both sides).
__global__ __launch_bounds__(512, 1) void lstm_persist(
    const _Float16* __restrict__ xb16,
    const _Float16* __restrict__ Wc0, const float* __restrict__ b0,
    const _Float16* __restrict__ Wc1, const float* __restrict__ b1,
    _Float16* __restrict__ h0a, _Float16* __restrict__ h0b,
    _Float16* __restrict__ h1a, _Float16* __restrict__ h1b,
    const _Float16* __restrict__ hz,
    unsigned* __restrict__ cnt)    // 16 groups x 16 uints (64B apart)
{
    __shared__ __align__(16) char lds[114688];
    const int bid     = blockIdx.x;
    const int hcb     = bid & 7;
    const int q       = bid >> 3;
    const int layer   = q & 1;
    const int rowtile = q >> 1;    // 0..15
    const int group   = rowtile;

    _Float16* h0r[2] = {h0a, h0b};
    _Float16* h1r[2] = {h1a, h1b};

    float creg[16];
#pragma unroll
    for (int i = 0; i < 16; ++i) creg[i] = 0.0f;

    for (int r = 0; r <= Tsz; ++r) {
        if (layer == 0) {
            if (r < Tsz) {
                const int t = r;
                const _Float16* hp = t ? h0r[(t - 1) & 1] : hz;
                step_p<128, 0, 16>(xb16 + (size_t)t * 128, Lsz, hp, Wc0, b0,
                                   creg, h0r[t & 1], rowtile, hcb, lds);
            }
        } else {
            if (r >= 1) {
                const int t = r - 1;
                const _Float16* hp = t ? h1r[(t - 1) & 1] : hz;
                step_p<512, 16, 16>(h0r[t & 1], 512, hp, Wc1, b1,
                                    creg, h1r[t & 1], rowtile, hcb, lds);
            }
        }
        if (r < Tsz) {
            // per-group barrier (16 arrivals). __syncthreads drains vmcnt (sc1 h stores
            // at IF), then monotonic counter arrive/spin (relaxed agent atomics).
            __syncthreads();
            if (threadIdx.x == 0) {
                unsigned* cp = cnt + group * 16;
                __hip_atomic_fetch_add(cp, 1u, __ATOMIC_RELAXED, __HIP_MEMORY_SCOPE_AGENT);
                const unsigned target = 16u * (r + 1);
                while (__hip_atomic_load(cp, __ATOMIC_RELAXED, __HIP_MEMORY_SCOPE_AGENT) < target)
                    __builtin_amdgcn_s_sleep(1);
            }
            __syncthreads();
            __builtin_amdgcn_sched_barrier(0);
        }
    }
}

__global__ void proj_kernel(const _Float16* __restrict__ h1,
                            const float* __restrict__ Wout,  // [10, 512]
                            const float* __restrict__ bout,  // [10]
                            float* __restrict__ out)         // [2048, 10]
{
    int tid = blockIdx.x * blockDim.x + threadIdx.x;
    if (tid >= Bsz * 10) return;
    int b = tid / 10, o = tid % 10;
    float s = bout[o];
    const _Float16* hrow = h1 + (size_t)b * 512;
    const float* wrow = Wout + (size_t)o * 512;
    for (int k = 0; k < 512; ++k) s += (float)hrow[k] * wrow[k];
    out[tid] = s;
}

extern "C" void kernel_launch(void* const* d_in, const int* in_sizes, int n_in,
                              void* d_out, int out_size, void* d_ws, size_t ws_size,
                              hipStream_t stream) {
    const float* xb    = (const float*)d_in[0];
    const float* W_ih0 = (const float*)d_in[1];
    const float* W_hh0 = (const float*)d_in[2];
    const float* b0    = (const float*)d_in[3];
    const float* W_ih1 = (const float*)d_in[4];
    const float* W_hh1 = (const float*)d_in[5];
    const float* b1    = (const float*)d_in[6];
    const float* W_out = (const float*)d_in[7];
    const float* b_out = (const float*)d_in[8];
    float* out = (float*)d_out;

    char* ws = (char*)d_ws;
    size_t off = 0;
    auto alloc = [&](size_t bytes) -> void* {
        void* p = ws + off;
        off += (bytes + 255) & ~(size_t)255;
        return p;
    };
    // ~49 MB << 256 MiB ws
    _Float16* xb16 = (_Float16*)alloc((size_t)Bsz * Lsz * 2);
    _Float16* Wc0  = (_Float16*)alloc((size_t)2048 * 640 * 2);
    _Float16* Wc1  = (_Float16*)alloc((size_t)2048 * 1024 * 2);
    _Float16* h0a  = (_Float16*)alloc(HS * 2);
    _Float16* h0b  = (_Float16*)alloc(HS * 2);
    _Float16* h1a  = (_Float16*)alloc(HS * 2);
    _Float16* h1b  = (_Float16*)alloc(HS * 2);
    _Float16* hz   = (_Float16*)alloc(HS * 2);
    unsigned* cnt  = (unsigned*)alloc(16 * 16 * 4);

    cvt_f32_f16<<<2048, 256, 0, stream>>>(xb, xb16, Bsz * Lsz / 4);
    pack_w<<<1280, 256, 0, stream>>>(W_ih0, W_hh0, Wc0, 128);
    pack_w<<<2048, 256, 0, stream>>>(W_ih1, W_hh1, Wc1, 512);

    hipMemsetAsync(hz, 0, HS * 2, stream);
    hipMemsetAsync(cnt, 0, 16 * 16 * 4, stream);   // barrier counters reset every launch

    lstm_persist<<<dim3(256), 512, 0, stream>>>(
        xb16, Wc0, b0, Wc1, b1, h0a, h0b, h1a, h1b, hz, cnt);

    // final h1 = step t=63 -> h1r[63&1] = h1b
    proj_kernel<<<(Bsz * 10 + 255) / 256, 256, 0, stream>>>(h1b, W_out, b_out, out);
}